// Round 2
// baseline (345.777 us; speedup 1.0000x reference)
//
#include <hip/hip_runtime.h>
#include <hip/hip_bf16.h>
#include <hip/hip_cooperative_groups.h>

namespace cg = cooperative_groups;

// CFAR via separable box sums — R8: revert hbox to R6 form (proven fast),
// fuse vscan+segscan+final into ONE cooperative kernel (2 launches total).
//   hbox : row prefix (padded LDS) -> horizontal 161/321 window diffs.
//          1024 blocks x 256 (one wave per row).
//   vsf  : cooperative, 1024 blocks x 256, 0 LDS, VGPR<=128 (4 blk/CU,
//          exactly co-resident).
//          V: in-place per-8-row-segment column scan + seg totals
//          S: exclusive scan of 128 seg totals per column (shuffle scan)
//          F: front = P(r+80)-P(r-81), allsum = P(r+160)-P(r-161),
//             P(rho) = g[rho] + SP[rho>>3]; out = SCALE*front/(allsum-front)
// BG_AREA = 321^2-161^2 = 77120 ; FRONT_DIV = 161^2*1.8 = 46657.8

#define IMG 4
#define H 1024
#define W 1024
#define SEGR 8
#define NSEG 128                   // H / SEGR
#define PADL 164
#define PADR 164
#define ROWLEN (PADL + W + PADR)   // 1352 floats per padded LDS row

// ---------------- Kernel 1: horizontal box sums (both widths) ---------------
// One wave per row. Padded prefix row in LDS (left pad = 0, right pad = row
// total) -> clamp-free phase 2. Phase 2: stride-64 scalar LDS reads (2-way
// aliasing = free), scalar coalesced global stores. [R6-proven]
__global__ __launch_bounds__(256) void hbox_kernel(const float* __restrict__ x,
                                                   float* __restrict__ h161,
                                                   float* __restrict__ h321) {
    __shared__ float P[4][ROWLEN];   // 21632 B
    const int wave = threadIdx.x >> 6;
    const int lane = threadIdx.x & 63;
    const int row  = (blockIdx.x << 2) + wave;   // 0..4095 flat over images

    const float4* xr = reinterpret_cast<const float4*>(x + (size_t)row * W);
    float v[16];
    {
        float4 a0 = xr[(lane << 2) + 0];
        float4 a1 = xr[(lane << 2) + 1];
        float4 a2 = xr[(lane << 2) + 2];
        float4 a3 = xr[(lane << 2) + 3];
        v[0]=a0.x; v[1]=a0.y; v[2]=a0.z; v[3]=a0.w;
        v[4]=a1.x; v[5]=a1.y; v[6]=a1.z; v[7]=a1.w;
        v[8]=a2.x; v[9]=a2.y; v[10]=a2.z; v[11]=a2.w;
        v[12]=a3.x; v[13]=a3.y; v[14]=a3.z; v[15]=a3.w;
    }
    float s = 0.f;
#pragma unroll
    for (int j = 0; j < 16; ++j) { s += v[j]; v[j] = s; }
    float t = s;
#pragma unroll
    for (int d = 1; d < 64; d <<= 1) {
        float u = __shfl_up(t, d, 64);
        if (lane >= d) t += u;
    }
    const float off = t - s;           // exclusive prefix of lane totals
#pragma unroll
    for (int j = 0; j < 16; ++j) v[j] += off;
    const float tot = __shfl(t, 63, 64);

    float* rowP = P[wave];
    float4* Pr = reinterpret_cast<float4*>(rowP + PADL);
    Pr[(lane << 2) + 0] = make_float4(v[0], v[1], v[2], v[3]);
    Pr[(lane << 2) + 1] = make_float4(v[4], v[5], v[6], v[7]);
    Pr[(lane << 2) + 2] = make_float4(v[8], v[9], v[10], v[11]);
    Pr[(lane << 2) + 3] = make_float4(v[12], v[13], v[14], v[15]);
    {   // pads: quads 0..40 = 0 (left), quads 297..337 = tot (right)
        float4* Pz = reinterpret_cast<float4*>(rowP);
        if (lane < 41) {
            Pz[lane]       = make_float4(0.f, 0.f, 0.f, 0.f);
            Pz[297 + lane] = make_float4(tot, tot, tot, tot);
        }
    }
    __syncthreads();

    const float* Pw = &P[wave][PADL];
    float* o161 = h161 + (size_t)row * W;
    float* o321 = h321 + (size_t)row * W;
#pragma unroll
    for (int k = 0; k < 16; ++k) {
        const int c = lane + (k << 6);
        const float s1 = Pw[c + 80]  - Pw[c - 81];
        const float s3 = Pw[c + 160] - Pw[c - 161];
        o161[c] = s1;
        o321[c] = s3;
    }
}

// ------- Kernel 2: cooperative vscan + segscan + final ---------------------
// 1024 blocks x 256 threads, 0 LDS. Phases separated by grid.sync().
__global__ __launch_bounds__(256, 4) void vsf_kernel(float* __restrict__ g161,
                                                     float* __restrict__ g321,
                                                     float* __restrict__ Btot,
                                                     float* __restrict__ SP,
                                                     float* __restrict__ out) {
    cg::grid_group grid = cg::this_grid();
    const int tid = threadIdx.x;
    const int bid = blockIdx.x;          // 0..1023

    // ---- Phase V: in-place per-segment column scan. unit = bid:
    //      buf = bid>>9, img = (bid>>7)&3, seg = bid&127. 8 rows x 1024 cols.
    {
        const int buf = bid >> 9;
        const int img = (bid >> 7) & 3;
        const int seg = bid & 127;
        float* b = buf ? g321 : g161;
        float4* p = reinterpret_cast<float4*>(
            b + ((size_t)img << 20) + ((size_t)(seg << 3) << 10)) + tid;
        float4 a[SEGR];
#pragma unroll
        for (int j = 0; j < SEGR; ++j) a[j] = p[(size_t)j << 8];
#pragma unroll
        for (int j = 1; j < SEGR; ++j) {
            a[j].x += a[j-1].x; a[j].y += a[j-1].y;
            a[j].z += a[j-1].z; a[j].w += a[j-1].w;
        }
#pragma unroll
        for (int j = 1; j < SEGR; ++j) p[(size_t)j << 8] = a[j];
        // seg totals: float layout [buf*4+img][seg][W]
        float4* bt = reinterpret_cast<float4*>(
            Btot + (((size_t)(buf << 2) + img) << 17) + ((size_t)seg << 10));
        bt[tid] = a[SEGR - 1];
    }
    grid.sync();

    // ---- Phase S: exclusive scan of 128 seg totals per column.
    //      8192 column-units (2 buf x 4 img x 1024 cols), 4096 waves x 2.
    {
        const int wv   = (bid << 2) + (tid >> 6);   // 0..4095
        const int lane = tid & 63;
#pragma unroll
        for (int k = 0; k < 2; ++k) {
            const int cu  = wv + (k << 12);         // 0..8191
            const int bi  = cu >> 10;               // buf*4+img
            const int col = cu & 1023;
            const float* bt = Btot + ((size_t)bi << 17) + col;
            float*       sp = SP   + ((size_t)bi << 17) + col;
            const float v0 = bt[(size_t)(lane << 1) << 10];
            const float v1 = bt[(size_t)((lane << 1) + 1) << 10];
            const float s  = v0 + v1;
            float t = s;
#pragma unroll
            for (int d = 1; d < 64; d <<= 1) {
                const float u = __shfl_up(t, d, 64);
                if (lane >= d) t += u;
            }
            const float e = t - s;                  // exclusive lane prefix
            sp[(size_t)(lane << 1) << 10]       = e;
            sp[(size_t)((lane << 1) + 1) << 10] = e + v0;
        }
    }
    grid.sync();

    // ---- Phase F: final window diffs. 4 rows per block, 256 quad-cols.
    {
        const float SCALE = (float)(77120.0 / 46657.8);   // BG_AREA / FRONT_DIV
        const int c4 = tid;
#pragma unroll
        for (int rr = 0; rr < 4; ++rr) {
            const int fr  = (bid << 2) + rr;        // flat row 0..4095
            const int img = fr >> 10;
            const int r   = fr & 1023;

            const float4* P1 = reinterpret_cast<const float4*>(g161 + ((size_t)img << 20));
            const float4* P3 = reinterpret_cast<const float4*>(g321 + ((size_t)img << 20));
            // SP float4 layout: [buf][img][NSEG][256] ; NSEG*256 = 1<<15
            const float4* SP1 = reinterpret_cast<const float4*>(SP) + ((size_t)img << 15);
            const float4* SP3 = reinterpret_cast<const float4*>(SP) + ((size_t)(IMG + img) << 15);

            const int hi1 = min(r + 80, H - 1),  lo1 = r - 81;
            const int hi3 = min(r + 160, H - 1), lo3 = r - 161;

            float4 f  = P1[((size_t)hi1 << 8) + c4];
            float4 fs = SP1[(((size_t)hi1 >> 3) << 8) + c4];
            float fx = f.x + fs.x, fy = f.y + fs.y, fz = f.z + fs.z, fw = f.w + fs.w;
            if (lo1 >= 0) {
                float4 g  = P1[((size_t)lo1 << 8) + c4];
                float4 gs = SP1[(((size_t)lo1 >> 3) << 8) + c4];
                fx -= g.x + gs.x; fy -= g.y + gs.y; fz -= g.z + gs.z; fw -= g.w + gs.w;
            }
            float4 a  = P3[((size_t)hi3 << 8) + c4];
            float4 as = SP3[(((size_t)hi3 >> 3) << 8) + c4];
            float ax = a.x + as.x, ay = a.y + as.y, az = a.z + as.z, aw = a.w + as.w;
            if (lo3 >= 0) {
                float4 g  = P3[((size_t)lo3 << 8) + c4];
                float4 gs = SP3[(((size_t)lo3 >> 3) << 8) + c4];
                ax -= g.x + gs.x; ay -= g.y + gs.y; az -= g.z + gs.z; aw -= g.w + gs.w;
            }

            float4 o;
            o.x = SCALE * fx * __builtin_amdgcn_rcpf(ax - fx);
            o.y = SCALE * fy * __builtin_amdgcn_rcpf(ay - fy);
            o.z = SCALE * fz * __builtin_amdgcn_rcpf(az - fz);
            o.w = SCALE * fw * __builtin_amdgcn_rcpf(aw - fw);
            reinterpret_cast<float4*>(out + ((size_t)img << 20) + ((size_t)r << 10))[c4] = o;
        }
    }
}

extern "C" void kernel_launch(void* const* d_in, const int* in_sizes, int n_in,
                              void* d_out, int out_size, void* d_ws, size_t ws_size,
                              hipStream_t stream) {
    const float* x = (const float*)d_in[0];
    float* outp = (float*)d_out;
    float* g161 = (float*)d_ws;                          // 16 MB (scanned in-place)
    float* g321 = g161 + (size_t)IMG * H * W;            // 16 MB (scanned in-place)
    float* Btot = g321 + (size_t)IMG * H * W;            // 4 MB (2*4*128*1024 fp32)
    float* SPb  = Btot + (size_t)2 * IMG * NSEG * W;     // 4 MB

    hbox_kernel<<<dim3((IMG * H) / 4), dim3(256), 0, stream>>>(x, g161, g321);

    void* args[] = {&g161, &g321, &Btot, &SPb, &outp};
    hipLaunchCooperativeKernel((void*)vsf_kernel, dim3(IMG * NSEG * 2),
                               dim3(256), args, 0, stream);
}

// Round 3
// 110.479 us; speedup vs baseline: 3.1298x; 3.1298x over previous
//
#include <hip/hip_runtime.h>
#include <hip/hip_bf16.h>

// CFAR via separable box sums — R9: R6 4-launch structure, rebalanced vscan.
//   hbox    : row prefix (padded LDS) -> horizontal 161/321 window diffs.
//             1024 blocks (one wave per row). [R6-proven, unchanged]
//   vscan   : in-place per-8-row-segment vertical inclusive scan (float4 per
//             thread) + seg totals. NSEG=128 -> 1024 blocks (was 256 = 1/CU).
//   segscan : exclusive scan of 128 segment totals per column — one wave per
//             column: lanes hold seg pairs, 64-lane shuffle scan. [R8-validated]
//   final   : front = P(r+80)-P(r-81), allsum = P(r+160)-P(r-161),
//             P(rho) = g[rho] + SP[rho>>3] ; out = SCALE*front/(allsum-front)
// BG_AREA = 321^2-161^2 = 77120 ; FRONT_DIV = 161^2*1.8 = 46657.8

#define IMG 4
#define H 1024
#define W 1024
#define SEGR 8
#define NSEG 128                   // H / SEGR
#define PADL 164
#define PADR 164
#define ROWLEN (PADL + W + PADR)   // 1352 floats per padded LDS row

// ---------------- Kernel 1: horizontal box sums (both widths) ---------------
// One wave per row. Padded prefix row in LDS (left pad = 0, right pad = row
// total) -> clamp-free phase 2. Phase 2: stride-64 scalar LDS reads (2-way
// aliasing = free), scalar coalesced global stores. [R6-proven]
__global__ __launch_bounds__(256) void hbox_kernel(const float* __restrict__ x,
                                                   float* __restrict__ h161,
                                                   float* __restrict__ h321) {
    __shared__ float P[4][ROWLEN];   // 21632 B
    const int wave = threadIdx.x >> 6;
    const int lane = threadIdx.x & 63;
    const int row  = (blockIdx.x << 2) + wave;   // 0..4095 flat over images

    const float4* xr = reinterpret_cast<const float4*>(x + (size_t)row * W);
    float v[16];
    {
        float4 a0 = xr[(lane << 2) + 0];
        float4 a1 = xr[(lane << 2) + 1];
        float4 a2 = xr[(lane << 2) + 2];
        float4 a3 = xr[(lane << 2) + 3];
        v[0]=a0.x; v[1]=a0.y; v[2]=a0.z; v[3]=a0.w;
        v[4]=a1.x; v[5]=a1.y; v[6]=a1.z; v[7]=a1.w;
        v[8]=a2.x; v[9]=a2.y; v[10]=a2.z; v[11]=a2.w;
        v[12]=a3.x; v[13]=a3.y; v[14]=a3.z; v[15]=a3.w;
    }
    float s = 0.f;
#pragma unroll
    for (int j = 0; j < 16; ++j) { s += v[j]; v[j] = s; }
    float t = s;
#pragma unroll
    for (int d = 1; d < 64; d <<= 1) {
        float u = __shfl_up(t, d, 64);
        if (lane >= d) t += u;
    }
    const float off = t - s;           // exclusive prefix of lane totals
#pragma unroll
    for (int j = 0; j < 16; ++j) v[j] += off;
    const float tot = __shfl(t, 63, 64);

    float* rowP = P[wave];
    float4* Pr = reinterpret_cast<float4*>(rowP + PADL);
    Pr[(lane << 2) + 0] = make_float4(v[0], v[1], v[2], v[3]);
    Pr[(lane << 2) + 1] = make_float4(v[4], v[5], v[6], v[7]);
    Pr[(lane << 2) + 2] = make_float4(v[8], v[9], v[10], v[11]);
    Pr[(lane << 2) + 3] = make_float4(v[12], v[13], v[14], v[15]);
    {   // pads: quads 0..40 = 0 (left), quads 297..337 = tot (right)
        float4* Pz = reinterpret_cast<float4*>(rowP);
        if (lane < 41) {
            Pz[lane]       = make_float4(0.f, 0.f, 0.f, 0.f);
            Pz[297 + lane] = make_float4(tot, tot, tot, tot);
        }
    }
    __syncthreads();

    const float* Pw = &P[wave][PADL];
    float* o161 = h161 + (size_t)row * W;
    float* o321 = h321 + (size_t)row * W;
#pragma unroll
    for (int k = 0; k < 16; ++k) {
        const int c = lane + (k << 6);
        const float s1 = Pw[c + 80]  - Pw[c - 81];
        const float s3 = Pw[c + 160] - Pw[c - 161];
        o161[c] = s1;
        o321[c] = s3;
    }
}

// ------- Kernel 2: in-place per-segment column prefix + totals -------------
// float4 per thread; block = (buf, img, seg). 8 rows per segment.
// grid = (IMG*NSEG, 2) = (512, 2) -> 1024 blocks (4/CU).
__global__ __launch_bounds__(256) void vscan_kernel(float* __restrict__ h161,
                                                    float* __restrict__ h321,
                                                    float* __restrict__ Btot) {
    const int img = blockIdx.x >> 7;
    const int seg = blockIdx.x & 127;
    const int q   = threadIdx.x;          // quad column 0..255

    float* buf = blockIdx.y ? h321 : h161;
    float4* p = reinterpret_cast<float4*>(
        buf + ((size_t)img << 20) + ((size_t)(seg << 3) << 10)) + q;

    float4 a[SEGR];
#pragma unroll
    for (int j = 0; j < SEGR; ++j) a[j] = p[(size_t)j << 8];
#pragma unroll
    for (int j = 1; j < SEGR; ++j) {
        a[j].x += a[j-1].x; a[j].y += a[j-1].y;
        a[j].z += a[j-1].z; a[j].w += a[j-1].w;
    }
#pragma unroll
    for (int j = 1; j < SEGR; ++j) p[(size_t)j << 8] = a[j];   // row 0 unchanged

    // totals, float layout [buf*IMG+img][seg][W]
    float4* bt = reinterpret_cast<float4*>(
        Btot + (((size_t)(blockIdx.y << 2) + img) << 17) + ((size_t)seg << 10));
    bt[q] = a[SEGR - 1];
}

// ------- Kernel 3: exclusive scan of 128 segment totals per column ---------
// One wave per (bufimg, column): lane holds segs {2*lane, 2*lane+1}; shuffle
// scan of pair sums, then intra-pair fixup. 8192 waves = 2048 blocks x 256.
__global__ __launch_bounds__(256) void segscan_kernel(const float* __restrict__ Btot,
                                                      float* __restrict__ SP) {
    const int wid  = (blockIdx.x << 2) + (threadIdx.x >> 6);  // 0..8191
    const int lane = threadIdx.x & 63;
    const int bi   = wid >> 10;        // buf*IMG+img, 0..7
    const int col  = wid & 1023;
    const size_t base = ((size_t)bi << 17) + col;

    const float v0 = Btot[base + ((size_t)(lane << 1) << 10)];
    const float v1 = Btot[base + ((size_t)((lane << 1) + 1) << 10)];
    const float s  = v0 + v1;
    float t = s;
#pragma unroll
    for (int d = 1; d < 64; d <<= 1) {
        const float u = __shfl_up(t, d, 64);
        if (lane >= d) t += u;
    }
    const float e = t - s;             // exclusive prefix of pair sums
    SP[base + ((size_t)(lane << 1) << 10)]       = e;
    SP[base + ((size_t)((lane << 1) + 1) << 10)] = e + v0;
}

// ------- Kernel 4: final — window diffs of full column prefixes ------------
// 512 threads = 2 rows x 256 quad-columns per block; rcp-based division.
__global__ __launch_bounds__(512) void final_kernel(const float* __restrict__ g161,
                                                    const float* __restrict__ g321,
                                                    const float* __restrict__ SP,
                                                    float* __restrict__ out) {
    const int img = blockIdx.x >> 9;
    const int r   = ((blockIdx.x & 511) << 1) + (threadIdx.x >> 8);
    const int c4  = threadIdx.x & 255;

    const float4* P1 = reinterpret_cast<const float4*>(g161 + ((size_t)img << 20));
    const float4* P3 = reinterpret_cast<const float4*>(g321 + ((size_t)img << 20));
    // SP float4 layout: [buf][img][NSEG][256] ; NSEG*256 = 1<<15 per (buf,img)
    const float4* SP1 = reinterpret_cast<const float4*>(SP) + ((size_t)img << 15);
    const float4* SP3 = reinterpret_cast<const float4*>(SP) + ((size_t)(IMG + img) << 15);

    const int hi1 = min(r + 80, H - 1),  lo1 = r - 81;
    const int hi3 = min(r + 160, H - 1), lo3 = r - 161;

    float4 f  = P1[((size_t)hi1 << 8) + c4];
    float4 fs = SP1[(((size_t)hi1 >> 3) << 8) + c4];
    float fx = f.x + fs.x, fy = f.y + fs.y, fz = f.z + fs.z, fw = f.w + fs.w;
    if (lo1 >= 0) {
        float4 g  = P1[((size_t)lo1 << 8) + c4];
        float4 gs = SP1[(((size_t)lo1 >> 3) << 8) + c4];
        fx -= g.x + gs.x; fy -= g.y + gs.y; fz -= g.z + gs.z; fw -= g.w + gs.w;
    }
    float4 a  = P3[((size_t)hi3 << 8) + c4];
    float4 as = SP3[(((size_t)hi3 >> 3) << 8) + c4];
    float ax = a.x + as.x, ay = a.y + as.y, az = a.z + as.z, aw = a.w + as.w;
    if (lo3 >= 0) {
        float4 g  = P3[((size_t)lo3 << 8) + c4];
        float4 gs = SP3[(((size_t)lo3 >> 3) << 8) + c4];
        ax -= g.x + gs.x; ay -= g.y + gs.y; az -= g.z + gs.z; aw -= g.w + gs.w;
    }

    const float SCALE = (float)(77120.0 / 46657.8);   // BG_AREA / FRONT_DIV
    float4 o;
    o.x = SCALE * fx * __builtin_amdgcn_rcpf(ax - fx);
    o.y = SCALE * fy * __builtin_amdgcn_rcpf(ay - fy);
    o.z = SCALE * fz * __builtin_amdgcn_rcpf(az - fz);
    o.w = SCALE * fw * __builtin_amdgcn_rcpf(aw - fw);
    reinterpret_cast<float4*>(out + ((size_t)img << 20) + ((size_t)r << 10))[c4] = o;
}

extern "C" void kernel_launch(void* const* d_in, const int* in_sizes, int n_in,
                              void* d_out, int out_size, void* d_ws, size_t ws_size,
                              hipStream_t stream) {
    const float* x = (const float*)d_in[0];
    float* outp = (float*)d_out;
    float* g161 = (float*)d_ws;                          // 16 MB (scanned in-place)
    float* g321 = g161 + (size_t)IMG * H * W;            // 16 MB (scanned in-place)
    float* Btot = g321 + (size_t)IMG * H * W;            // 4 MB (2*4*128*1024 fp32)
    float* SPb  = Btot + (size_t)2 * IMG * NSEG * W;     // 4 MB

    hbox_kernel<<<dim3((IMG * H) / 4), dim3(256), 0, stream>>>(x, g161, g321);
    vscan_kernel<<<dim3(IMG * NSEG, 2), dim3(256), 0, stream>>>(g161, g321, Btot);
    segscan_kernel<<<dim3(2048), dim3(256), 0, stream>>>(Btot, SPb);
    final_kernel<<<dim3(IMG * (H / 2)), dim3(512), 0, stream>>>(g161, g321, SPb, outp);
}

// Round 4
// 90.370 us; speedup vs baseline: 3.8262x; 1.2225x over previous
//
#include <hip/hip_runtime.h>
#include <hip/hip_bf16.h>

// CFAR via separable box sums — R10: R7's fused hbv (proven −11 µs) +
// coalesced hierarchical segscan (kills R7/R9's 16x gather amplification) +
// R9's final. 3 launches.
//   hbv     : per 8-row segment: row prefix (padded LDS) -> horizontal
//             161/321 window diffs -> per-column running prefix (registers,
//             cross-wave handoff via time-shared 16 KB LDS) -> write SCANNED
//             values + segment totals. 512 blocks, 38 KB LDS.
//   segscan : exclusive scan of 128 segment totals per column. Block =
//             (bufimg, 64-col group); wave w register-loads segs 32w..32w+31
//             COALESCED, in-lane scan, cross-wave fixup via LDS. 128 blocks.
//   final   : front = P(r+80)-P(r-81), allsum = P(r+160)-P(r-161),
//             P(rho) = g[rho] + SP[rho>>3] ; out = SCALE*front/(allsum-front)
// BG_AREA = 321^2-161^2 = 77120 ; FRONT_DIV = 161^2*1.8 = 46657.8

#define IMG 4
#define H 1024
#define W 1024
#define SEGR 8
#define NSEG 128                   // H / SEGR
#define PADL 164
#define PADR 164
#define ROWLEN (PADL + W + PADR)   // 1352 floats per padded LDS row

// ------- Kernel 1: horizontal box sums + in-register vertical segment scan --
// One block per (img, seg): 4 waves x 2 chunks = 8 rows. [R7-verified]
__global__ __launch_bounds__(256, 4) void hbv_kernel(const float* __restrict__ x,
                                                     float* __restrict__ g161,
                                                     float* __restrict__ g321,
                                                     float* __restrict__ Btot) {
    __shared__ float P[4][ROWLEN];   // 21632 B — per-wave padded prefix row
    __shared__ float Hx[4][W];       // 16384 B — shared between 161/321 passes
    const int wave = threadIdx.x >> 6;
    const int lane = threadIdx.x & 63;
    const int q    = threadIdx.x;            // quad-column 0..255
    const int blk  = blockIdx.x;             // img*NSEG + seg
    const size_t rowbase = (size_t)blk << 3; // first flat row of segment

    float4 acc1 = make_float4(0.f, 0.f, 0.f, 0.f);
    float4 acc3 = make_float4(0.f, 0.f, 0.f, 0.f);

#pragma unroll
    for (int ch = 0; ch < 2; ++ch) {
        const size_t row = rowbase + (ch << 2) + wave;
        // ---- phase 1: row prefix into padded LDS row (per wave, own row)
        {
            const float4* xr = reinterpret_cast<const float4*>(x + row * W);
            float v[16];
            float4 a0 = xr[(lane << 2) + 0];
            float4 a1 = xr[(lane << 2) + 1];
            float4 a2 = xr[(lane << 2) + 2];
            float4 a3 = xr[(lane << 2) + 3];
            v[0]=a0.x; v[1]=a0.y; v[2]=a0.z; v[3]=a0.w;
            v[4]=a1.x; v[5]=a1.y; v[6]=a1.z; v[7]=a1.w;
            v[8]=a2.x; v[9]=a2.y; v[10]=a2.z; v[11]=a2.w;
            v[12]=a3.x; v[13]=a3.y; v[14]=a3.z; v[15]=a3.w;
            float s = 0.f;
#pragma unroll
            for (int j = 0; j < 16; ++j) { s += v[j]; v[j] = s; }
            float t = s;
#pragma unroll
            for (int d = 1; d < 64; d <<= 1) {
                float u = __shfl_up(t, d, 64);
                if (lane >= d) t += u;
            }
            const float off = t - s;        // exclusive prefix of lane totals
#pragma unroll
            for (int j = 0; j < 16; ++j) v[j] += off;
            const float tot = __shfl(t, 63, 64);

            float* rowP = P[wave];
            float4* Pr = reinterpret_cast<float4*>(rowP + PADL);
            Pr[(lane << 2) + 0] = make_float4(v[0], v[1], v[2], v[3]);
            Pr[(lane << 2) + 1] = make_float4(v[4], v[5], v[6], v[7]);
            Pr[(lane << 2) + 2] = make_float4(v[8], v[9], v[10], v[11]);
            Pr[(lane << 2) + 3] = make_float4(v[12], v[13], v[14], v[15]);
            // pads: quads 0..40 = 0 (left), quads 297..337 = tot (right)
            float4* Pz = reinterpret_cast<float4*>(rowP);
            if (lane < 41) {
                Pz[lane]       = make_float4(0.f, 0.f, 0.f, 0.f);
                Pz[297 + lane] = make_float4(tot, tot, tot, tot);
            }
        }
        const float* Pw = &P[wave][PADL];   // only this wave reads its P row

        // ---- phase 2a: 161-window diffs into Hx (row-major by wave)
#pragma unroll
        for (int k = 0; k < 16; ++k) {
            const int c = lane + (k << 6);
            Hx[wave][c] = Pw[c + 80] - Pw[c - 81];
        }
        __syncthreads();
        // ---- phase 3a: column-prefix accumulate + store scanned g161 rows
        {
            float* o = g161 + (rowbase + (ch << 2)) * W;
            const float4* Hf = reinterpret_cast<const float4*>(Hx);
#pragma unroll
            for (int r = 0; r < 4; ++r) {
                float4 h = Hf[(r << 8) + q];
                acc1.x += h.x; acc1.y += h.y; acc1.z += h.z; acc1.w += h.w;
                reinterpret_cast<float4*>(o + (size_t)r * W)[q] = acc1;
            }
        }
        __syncthreads();
        // ---- phase 2b: 321-window diffs into Hx (reuse buffer)
#pragma unroll
        for (int k = 0; k < 16; ++k) {
            const int c = lane + (k << 6);
            Hx[wave][c] = Pw[c + 160] - Pw[c - 161];
        }
        __syncthreads();
        // ---- phase 3b
        {
            float* o = g321 + (rowbase + (ch << 2)) * W;
            const float4* Hf = reinterpret_cast<const float4*>(Hx);
#pragma unroll
            for (int r = 0; r < 4; ++r) {
                float4 h = Hf[(r << 8) + q];
                acc3.x += h.x; acc3.y += h.y; acc3.z += h.z; acc3.w += h.w;
                reinterpret_cast<float4*>(o + (size_t)r * W)[q] = acc3;
            }
        }
        __syncthreads();   // Hx reused by next chunk's phase 2a
    }

    // ---- segment totals: float layout [buf*IMG+img][seg][W]
    const int img = blk >> 7;
    const int seg = blk & 127;
    float4* bt = reinterpret_cast<float4*>(Btot);
    bt[((size_t)img << 15)         + (seg << 8) + q] = acc1;
    bt[((size_t)(IMG + img) << 15) + (seg << 8) + q] = acc3;
}

// ------- Kernel 2: exclusive scan of 128 segment totals per column ---------
// Block = (bufimg, 64-col group), 4 waves. Wave w: segs 32w..32w+31 into
// registers via 32 COALESCED 256 B loads, in-lane exclusive scan, wave
// totals -> LDS, cross-wave offset, coalesced stores. 128 blocks x 256.
__global__ __launch_bounds__(256) void segscan_kernel(const float* __restrict__ Btot,
                                                      float* __restrict__ SP) {
    __shared__ float T[4][64];
    const int wave = threadIdx.x >> 6;
    const int lane = threadIdx.x & 63;
    const int bi   = blockIdx.x >> 4;                    // buf*IMG+img, 0..7
    const int col  = ((blockIdx.x & 15) << 6) + lane;    // 0..1023
    const size_t base = ((size_t)bi << 17) + ((size_t)(wave << 5) << 10) + col;

    float v[32];
#pragma unroll
    for (int s = 0; s < 32; ++s) v[s] = Btot[base + ((size_t)s << 10)];
    float run = 0.f;
#pragma unroll
    for (int s = 0; s < 32; ++s) { const float t = v[s]; v[s] = run; run += t; }
    T[wave][lane] = run;
    __syncthreads();
    float off = 0.f;
    for (int w = 0; w < wave; ++w) off += T[w][lane];    // wave-uniform trip
#pragma unroll
    for (int s = 0; s < 32; ++s) SP[base + ((size_t)s << 10)] = v[s] + off;
}

// ------- Kernel 3: final — window diffs of full column prefixes ------------
// 512 threads = 2 rows x 256 quad-columns per block; rcp-based division.
__global__ __launch_bounds__(512) void final_kernel(const float* __restrict__ g161,
                                                    const float* __restrict__ g321,
                                                    const float* __restrict__ SP,
                                                    float* __restrict__ out) {
    const int img = blockIdx.x >> 9;
    const int r   = ((blockIdx.x & 511) << 1) + (threadIdx.x >> 8);
    const int c4  = threadIdx.x & 255;

    const float4* P1 = reinterpret_cast<const float4*>(g161 + ((size_t)img << 20));
    const float4* P3 = reinterpret_cast<const float4*>(g321 + ((size_t)img << 20));
    // SP float4 layout: [buf][img][NSEG][256] ; NSEG*256 = 1<<15 per (buf,img)
    const float4* SP1 = reinterpret_cast<const float4*>(SP) + ((size_t)img << 15);
    const float4* SP3 = reinterpret_cast<const float4*>(SP) + ((size_t)(IMG + img) << 15);

    const int hi1 = min(r + 80, H - 1),  lo1 = r - 81;
    const int hi3 = min(r + 160, H - 1), lo3 = r - 161;

    float4 f  = P1[((size_t)hi1 << 8) + c4];
    float4 fs = SP1[(((size_t)hi1 >> 3) << 8) + c4];
    float fx = f.x + fs.x, fy = f.y + fs.y, fz = f.z + fs.z, fw = f.w + fs.w;
    if (lo1 >= 0) {
        float4 g  = P1[((size_t)lo1 << 8) + c4];
        float4 gs = SP1[(((size_t)lo1 >> 3) << 8) + c4];
        fx -= g.x + gs.x; fy -= g.y + gs.y; fz -= g.z + gs.z; fw -= g.w + gs.w;
    }
    float4 a  = P3[((size_t)hi3 << 8) + c4];
    float4 as = SP3[(((size_t)hi3 >> 3) << 8) + c4];
    float ax = a.x + as.x, ay = a.y + as.y, az = a.z + as.z, aw = a.w + as.w;
    if (lo3 >= 0) {
        float4 g  = P3[((size_t)lo3 << 8) + c4];
        float4 gs = SP3[(((size_t)lo3 >> 3) << 8) + c4];
        ax -= g.x + gs.x; ay -= g.y + gs.y; az -= g.z + gs.z; aw -= g.w + gs.w;
    }

    const float SCALE = (float)(77120.0 / 46657.8);   // BG_AREA / FRONT_DIV
    float4 o;
    o.x = SCALE * fx * __builtin_amdgcn_rcpf(ax - fx);
    o.y = SCALE * fy * __builtin_amdgcn_rcpf(ay - fy);
    o.z = SCALE * fz * __builtin_amdgcn_rcpf(az - fz);
    o.w = SCALE * fw * __builtin_amdgcn_rcpf(aw - fw);
    reinterpret_cast<float4*>(out + ((size_t)img << 20) + ((size_t)r << 10))[c4] = o;
}

extern "C" void kernel_launch(void* const* d_in, const int* in_sizes, int n_in,
                              void* d_out, int out_size, void* d_ws, size_t ws_size,
                              hipStream_t stream) {
    const float* x = (const float*)d_in[0];
    float* outp = (float*)d_out;
    float* g161 = (float*)d_ws;                          // 16 MB (scanned)
    float* g321 = g161 + (size_t)IMG * H * W;            // 16 MB (scanned)
    float* Btot = g321 + (size_t)IMG * H * W;            // 4 MB (2*4*128*1024 fp32)
    float* SPb  = Btot + (size_t)2 * IMG * NSEG * W;     // 4 MB

    hbv_kernel<<<dim3(IMG * NSEG), dim3(256), 0, stream>>>(x, g161, g321, Btot);
    segscan_kernel<<<dim3(128), dim3(256), 0, stream>>>(Btot, SPb);
    final_kernel<<<dim3(IMG * (H / 2)), dim3(512), 0, stream>>>(g161, g321, SPb, outp);
}